// Round 2
// baseline (207.879 us; speedup 1.0000x reference)
//
#include <hip/hip_runtime.h>
#include <hip/hip_bf16.h>

typedef _Float16 f16;
typedef f16 f16x8 __attribute__((ext_vector_type(8)));
typedef f16 f16x4 __attribute__((ext_vector_type(4)));
typedef float f32x4 __attribute__((ext_vector_type(4)));

#define MFMA16(a, b, c) __builtin_amdgcn_mfma_f32_16x16x32_f16((a), (b), (c), 0, 0, 0)

// ---- ws layout (float offsets) ----
#define OFF_REL    0          // 4096 floats: rel[b*256+d]
#define OFF_Y      4096       // 1,089,536 floats: [spt_pos 20480][spt_neg 20480][qry 1048576]
#define OFF_PROTO  1093632    // 4096
#define OFF_SNEG   1097728    // 4096
#define OFF_SUMS   1101824    // 2 floats (pos_sum, neg_sum)
#define OFF_W      1101828    // f16 region: 29 frags * 64 lanes * 8 halves

// element space: [0,20480) spt_pos, [20480,40960) spt_neg, [40960,1089536) qry
// chunks of 16 elements: 68096 chunks total

// ---------------- prep: rel + weight fragment packing ----------------
__global__ void k_prep(const float* __restrict__ sup, const float* __restrict__ supn,
                       const float* __restrict__ w1, const float* __restrict__ b1,
                       const float* __restrict__ w2, const float* __restrict__ w3,
                       const float* __restrict__ w4, float* __restrict__ ws)
{
    int tid = threadIdx.x;
    if (blockIdx.x < 16) {
        int idx = blockIdx.x * 256 + tid;     // (b,d)
        int b = idx >> 8, d = idx & 255;
        float acc = 0.f;
        #pragma unroll
        for (int n = 0; n < 5; n++) {
            const float* base = sup + ((b * 5 + n) * 2) * 256 + d;
            acc += base[256] - base[0];
        }
        ws[OFF_REL + idx] = acc * 0.2f;
    } else {
        // pack 29 MFMA A-operand weight fragments (f16), per-lane contiguous 8 halves
        f16* wf = (f16*)(ws + OFF_W);
        for (int id = tid; id < 29 * 64; id += 256) {
            int frag = id >> 6, lane = id & 63;
            int g = lane >> 4, cr = lane & 15, kb = g * 8;
            float vals[8];
            if (frag < 8) {                       // L1: W1 (128x3) + b1 folded at k==3
                int out = frag * 16 + cr;
                #pragma unroll
                for (int i = 0; i < 8; i++) {
                    int k = kb + i;
                    vals[i] = (k < 3) ? w1[out * 3 + k] : (k == 3 ? b1[out] : 0.f);
                }
            } else if (frag < 24) {               // L2: W2 (64x128)
                int f = frag - 8; int t = f >> 2, kk = f & 3; int out = t * 16 + cr;
                #pragma unroll
                for (int i = 0; i < 8; i++) vals[i] = w2[out * 128 + kk * 32 + kb + i];
            } else if (frag < 28) {               // L3: W3 (32x64)
                int f = frag - 24; int t = f >> 1, kk = f & 1; int out = t * 16 + cr;
                #pragma unroll
                for (int i = 0; i < 8; i++) vals[i] = w3[out * 64 + kk * 32 + kb + i];
            } else {                              // L4: W4 (1x32), rows 1..15 zero
                #pragma unroll
                for (int i = 0; i < 8; i++) vals[i] = (cr == 0) ? w4[kb + i] : 0.f;
            }
            #pragma unroll
            for (int i = 0; i < 8; i++) wf[id * 8 + i] = (f16)vals[i];
        }
    }
}

// ---------------- main fused MLP (f16 MFMA, transposed GEMM) ----------------
// LDS strides in halves (padded for bank spread): tile1 16x136, tile2 16x72, tile3 16x40
#define WLDS (16 * 136 + 16 * 72 + 16 * 40)   // 3968 halves = 7936 B per wave

__global__ __launch_bounds__(256) void k_main(
    const float* __restrict__ sup, const float* __restrict__ supn,
    const float* __restrict__ qry, const float* __restrict__ neg,
    const float* __restrict__ b2p, const float* __restrict__ b3p,
    const float* __restrict__ b4p, float* __restrict__ ws)
{
    __shared__ __align__(16) f16 lds[4 * WLDS];
    const float* wsRel = ws + OFF_REL;
    float* wsY = ws + OFF_Y;
    const f16x8* wf = (const f16x8*)(ws + OFF_W);

    int tid = threadIdx.x, wv = tid >> 6, lane = tid & 63;
    int g = lane >> 4, col = lane & 15;
    f16* t1 = lds + wv * WLDS;
    f16* t2 = t1 + 16 * 136;
    f16* t3 = t2 + 16 * 72;

    const f32x4 zero4 = {0.f, 0.f, 0.f, 0.f};

    // preload weight fragments into registers (reused over 16 chunks)
    f16x8 w1f[8], w2f[16], w3f[4], w4f;
    #pragma unroll
    for (int f = 0; f < 8; f++)  w1f[f] = wf[f * 64 + lane];
    #pragma unroll
    for (int f = 0; f < 16; f++) w2f[f] = wf[(8 + f) * 64 + lane];
    #pragma unroll
    for (int f = 0; f < 4; f++)  w3f[f] = wf[(24 + f) * 64 + lane];
    w4f = wf[28 * 64 + lane];

    // biases folded into accumulator init: C row = out = g*4 + reg (+16t)
    f32x4 bias2[4], bias3[2];
    #pragma unroll
    for (int t = 0; t < 4; t++) {
        int o = t * 16 + g * 4;
        bias2[t] = (f32x4){b2p[o], b2p[o + 1], b2p[o + 2], b2p[o + 3]};
    }
    #pragma unroll
    for (int t = 0; t < 2; t++) {
        int o = t * 16 + g * 4;
        bias3[t] = (f32x4){b3p[o], b3p[o + 1], b3p[o + 2], b3p[o + 3]};
    }
    float b4v = b4p[0];

    for (int it = 0; it < 16; ++it) {
        int chunk = (blockIdx.x * 4 + wv) * 16 + it;

        // ---- build B1 fragment: X^T tile (k x elem); k: 0=head,1=rel,2=tail,3=1.0 ----
        f16x8 bf1 = {(f16)0.f, (f16)0.f, (f16)0.f, (f16)0.f,
                     (f16)0.f, (f16)0.f, (f16)0.f, (f16)0.f};
        if (g == 0) {
            int e = chunk * 16 + col;
            const float* hp; int b, d;
            if (e < 40960) {
                const float* srcp = (e < 20480) ? sup : supn;
                int e2 = (e < 20480) ? e : e - 20480;
                b = e2 / 1280; int r = e2 % 1280; int n = r >> 8; d = r & 255;
                hp = srcp + ((b * 5 + n) * 2) * 256 + d;
            } else {
                int e2 = e - 40960;
                b = e2 >> 16; int r = e2 & 65535; int m = r >> 8; d = r & 255;
                hp = (m < 128) ? (qry + ((b * 128 + m) * 2) * 256 + d)
                               : (neg + ((b * 128 + (m - 128)) * 2) * 256 + d);
            }
            float x0 = hp[0], x2 = hp[256], x1 = wsRel[b * 256 + d];
            bf1[0] = (f16)x0; bf1[1] = (f16)x1; bf1[2] = (f16)x2; bf1[3] = (f16)1.0f;
        }

        // ---- L1: 128 outs = 8 tiles, K=32 (3 used + bias slot) ----
        #pragma unroll
        for (int t = 0; t < 8; t++) {
            f32x4 c = MFMA16(w1f[t], bf1, zero4);
            f16x4 v;
            #pragma unroll
            for (int r = 0; r < 4; r++) v[r] = (f16)fmaxf(c[r], 0.f);
            *(f16x4*)(t1 + col * 136 + t * 16 + g * 4) = v;   // [elem][out]
        }

        // ---- L2: 64 outs = 4 tiles, K=128 = 4 ksteps ----
        f16x8 bf2[4];
        #pragma unroll
        for (int kk = 0; kk < 4; kk++)
            bf2[kk] = *(const f16x8*)(t1 + col * 136 + kk * 32 + g * 8);
        #pragma unroll
        for (int t = 0; t < 4; t++) {
            f32x4 c = bias2[t];
            #pragma unroll
            for (int kk = 0; kk < 4; kk++) c = MFMA16(w2f[t * 4 + kk], bf2[kk], c);
            f16x4 v;
            #pragma unroll
            for (int r = 0; r < 4; r++) v[r] = (f16)fmaxf(c[r], 0.f);
            *(f16x4*)(t2 + col * 72 + t * 16 + g * 4) = v;
        }

        // ---- L3: 32 outs = 2 tiles, K=64 = 2 ksteps ----
        f16x8 bf3[2];
        #pragma unroll
        for (int kk = 0; kk < 2; kk++)
            bf3[kk] = *(const f16x8*)(t2 + col * 72 + kk * 32 + g * 8);
        #pragma unroll
        for (int t = 0; t < 2; t++) {
            f32x4 c = bias3[t];
            #pragma unroll
            for (int kk = 0; kk < 2; kk++) c = MFMA16(w3f[t * 2 + kk], bf3[kk], c);
            f16x4 v;
            #pragma unroll
            for (int r = 0; r < 4; r++) v[r] = (f16)fmaxf(c[r], 0.f);
            *(f16x4*)(t3 + col * 40 + t * 16 + g * 4) = v;
        }

        // ---- L4: 1 out, K=32 ----
        f16x8 bf4 = *(const f16x8*)(t3 + col * 40 + g * 8);
        f32x4 c4 = MFMA16(w4f, bf4, zero4);
        if (lane < 16) wsY[chunk * 16 + lane] = c4[0] + b4v;   // row0 = out0, col = elem
    }
}

// ---------------- proto / sneg means ----------------
__global__ void k_means(float* __restrict__ ws)
{
    int idx = blockIdx.x * 256 + threadIdx.x;   // 4096 = (b,d)
    int b = idx >> 8, d = idx & 255;
    const float* y = ws + OFF_Y;
    float sp = 0.f, sn = 0.f;
    #pragma unroll
    for (int n = 0; n < 5; n++) {
        sp += y[b * 1280 + n * 256 + d];
        sn += y[20480 + b * 1280 + n * 256 + d];
    }
    ws[OFF_PROTO + idx] = sp * 0.2f;
    ws[OFF_SNEG + idx] = sn * 0.2f;
}

// ---------------- scores: one wave per (b,m) row ----------------
__global__ __launch_bounds__(256) void k_scores(float* __restrict__ ws, float* __restrict__ out)
{
    int row = blockIdx.x * 4 + (threadIdx.x >> 6);   // 0..4095
    int lane = threadIdx.x & 63;
    int b = row >> 8, m = row & 255;
    const float* q = ws + OFF_Y + 40960 + row * 256;
    float q0 = q[lane], q1 = q[lane + 64], q2 = q[lane + 128], q3 = q[lane + 192];

    float s[17];
    #pragma unroll
    for (int c = 0; c < 16; c++) {
        const float* p = ws + OFF_PROTO + c * 256;
        float d0 = q0 - p[lane], d1 = q1 - p[lane + 64];
        float d2 = q2 - p[lane + 128], d3 = q3 - p[lane + 192];
        s[c] = d0 * d0 + d1 * d1 + d2 * d2 + d3 * d3;
    }
    {
        const float* p = ws + OFF_SNEG + b * 256;
        float d0 = q0 - p[lane], d1 = q1 - p[lane + 64];
        float d2 = q2 - p[lane + 128], d3 = q3 - p[lane + 192];
        s[16] = d0 * d0 + d1 * d1 + d2 * d2 + d3 * d3;
    }
    #pragma unroll
    for (int off = 32; off > 0; off >>= 1) {
        #pragma unroll
        for (int c = 0; c < 17; c++) s[c] += __shfl_xor(s[c], off, 64);
    }
    float sumd = 0.f, selfd = 0.f;
    #pragma unroll
    for (int c = 0; c < 16; c++) {
        float dc = sqrtf(s[c]);
        sumd += dc;
        if (c == b) selfd = dc;   // select, avoids runtime-indexed array
    }
    float qpos = -selfd;
    float qneg = -sqrtf(s[16]);
    float relation = -(sumd - selfd) * (1.f / 15.f);
    float delta = qpos - qneg - 0.3f * relation;

    if (lane == 0) {
        out[2 * row] = qpos;
        out[2 * row + 1] = qneg;
        out[8192 + row] = (m < 128) ? 0.f : 1.f;
        float* sums = ws + OFF_SUMS;
        if (m < 128) {
            out[12288 + b * 128 + m] = delta;
            atomicAdd(&sums[0], qpos);
            atomicAdd(&sums[1], qneg);
        } else {
            out[14336 + b * 128 + (m - 128)] = delta;
        }
    }
}

// ---------------- delta_loss finisher ----------------
__global__ void k_final(const float* __restrict__ ws, float* __restrict__ out)
{
    if (threadIdx.x == 0) {
        float v = (ws[OFF_SUMS] - ws[OFF_SUMS + 1]) * (1.f / 2048.f) + 1.f;
        out[16384] = fmaxf(v, 0.f);
    }
}

extern "C" void kernel_launch(void* const* d_in, const int* in_sizes, int n_in,
                              void* d_out, int out_size, void* d_ws, size_t ws_size,
                              hipStream_t stream)
{
    const float* sup  = (const float*)d_in[0];
    const float* supn = (const float*)d_in[1];
    const float* qry  = (const float*)d_in[2];
    const float* neg  = (const float*)d_in[3];
    const float* w1   = (const float*)d_in[4];
    const float* b1   = (const float*)d_in[5];
    const float* w2   = (const float*)d_in[6];
    const float* b2   = (const float*)d_in[7];
    const float* w3   = (const float*)d_in[8];
    const float* b3   = (const float*)d_in[9];
    const float* w4   = (const float*)d_in[10];
    const float* b4   = (const float*)d_in[11];
    float* ws  = (float*)d_ws;
    float* out = (float*)d_out;

    (void)hipMemsetAsync(ws + OFF_SUMS, 0, 2 * sizeof(float), stream);
    k_prep  <<<17,   256, 0, stream>>>(sup, supn, w1, b1, w2, w3, w4, ws);
    k_main  <<<1064, 256, 0, stream>>>(sup, supn, qry, neg, b2, b3, b4, ws);
    k_means <<<16,   256, 0, stream>>>(ws);
    k_scores<<<1024, 256, 0, stream>>>(ws, out);
    k_final <<<1,    64,  0, stream>>>(ws, out);
}

// Round 5
// 202.593 us; speedup vs baseline: 1.0261x; 1.0261x over previous
//
#include <hip/hip_runtime.h>
#include <hip/hip_bf16.h>

typedef _Float16 f16;
typedef f16 f16x8 __attribute__((ext_vector_type(8)));
typedef float f32x4 __attribute__((ext_vector_type(4)));
typedef unsigned int u32;

#define MFMA16(a, b, c) __builtin_amdgcn_mfma_f32_16x16x32_f16((a), (b), (c), 0, 0, 0)

__device__ __forceinline__ u32 pkrz(float a, float b) {
    auto r = __builtin_amdgcn_cvt_pkrtz(a, b);   // __fp16 ext_vector(2)
    return __builtin_bit_cast(u32, r);
}
__device__ __forceinline__ u32 pkrelu(float a, float b) {
    return pkrz(fmaxf(a, 0.f), fmaxf(b, 0.f));
}

union U8 { f16x8 h; u32 w[4]; };

// ---- ws layout (float offsets) ----
#define OFF_REL    0          // 4096 floats: rel[b*256+d]
#define OFF_Y      4096       // 1,089,536 floats: [spt_pos 20480][spt_neg 20480][qry 1048576]
#define OFF_PROTO  1093632    // 4096
#define OFF_SNEG   1097728    // 4096
#define OFF_SUMS   1101824    // 2 floats
#define OFF_W      1101828    // f16 region: 29 frags * 64 lanes * 8 halves

// ---------------- prep: rel + weight fragment packing ----------------
// Hidden-channel permutation: B-position (kk,g,i) holds C-slot
// (2kk + (i>>2))*16 + g*4 + (i&3) of the previous layer, so the layer
// transition is pure in-register relu+pack (no LDS / shuffles).
__global__ void k_prep(const float* __restrict__ sup, const float* __restrict__ supn,
                       const float* __restrict__ w1, const float* __restrict__ b1,
                       const float* __restrict__ w2, const float* __restrict__ w3,
                       const float* __restrict__ w4, float* __restrict__ ws)
{
    int tid = threadIdx.x;
    if (blockIdx.x < 16) {
        int idx = blockIdx.x * 256 + tid;     // (b,d)
        int b = idx >> 8, d = idx & 255;
        float acc = 0.f;
        #pragma unroll
        for (int n = 0; n < 5; n++) {
            const float* base = sup + ((b * 5 + n) * 2) * 256 + d;
            acc += base[256] - base[0];
        }
        ws[OFF_REL + idx] = acc * 0.2f;
    } else {
        f16* wf = (f16*)(ws + OFF_W);
        for (int id = tid; id < 29 * 64; id += 256) {
            int frag = id >> 6, lane = id & 63;
            int g = lane >> 4, cr = lane & 15, kb = g * 8;
            float vals[8];
            if (frag < 8) {                       // L1: W1 (128x3) + b1 folded at k==3
                int out = frag * 16 + cr;
                #pragma unroll
                for (int i = 0; i < 8; i++) {
                    int k = kb + i;
                    vals[i] = (k < 3) ? w1[out * 3 + k] : (k == 3 ? b1[out] : 0.f);
                }
            } else if (frag < 24) {               // L2: W2 (64x128), permuted input cols
                int f = frag - 8; int t = f >> 2, kk = f & 3; int out = t * 16 + cr;
                #pragma unroll
                for (int i = 0; i < 8; i++) {
                    int u = (2 * kk + (i >> 2)) * 16 + g * 4 + (i & 3);
                    vals[i] = w2[out * 128 + u];
                }
            } else if (frag < 28) {               // L3: W3 (32x64), permuted input cols
                int f = frag - 24; int t = f >> 1, kk = f & 1; int out = t * 16 + cr;
                #pragma unroll
                for (int i = 0; i < 8; i++) {
                    int u = (2 * kk + (i >> 2)) * 16 + g * 4 + (i & 3);
                    vals[i] = w3[out * 64 + u];
                }
            } else {                              // L4: W4 (1x32), permuted, rows 1..15 zero
                #pragma unroll
                for (int i = 0; i < 8; i++) {
                    int u = (i >> 2) * 16 + g * 4 + (i & 3);
                    vals[i] = (cr == 0) ? w4[u] : 0.f;
                }
            }
            #pragma unroll
            for (int i = 0; i < 8; i++) wf[id * 8 + i] = (f16)vals[i];
        }
    }
}

// ---------------- main fused MLP: all-register layer chain ----------------
// 532 blocks x 4 waves x 8 iters x 64 elems = 1,089,536
__global__ __launch_bounds__(256) void k_main(
    const float* __restrict__ sup, const float* __restrict__ supn,
    const float* __restrict__ qry, const float* __restrict__ neg,
    const float* __restrict__ b2p, const float* __restrict__ b3p,
    const float* __restrict__ b4p, float* __restrict__ ws)
{
    __shared__ uint2 stage[4][64];                 // 2 KB/block
    const float* wsRel = ws + OFF_REL;
    float* wsY = ws + OFF_Y;
    const f16x8* wf = (const f16x8*)(ws + OFF_W);

    int tid = threadIdx.x, wv = tid >> 6, lane = tid & 63;
    int g = lane >> 4, col = lane & 15;
    const f32x4 zero4 = {0.f, 0.f, 0.f, 0.f};

    // register-resident weight fragments (reused over 8*4 tiles)
    f16x8 w1f[8], w2f[16], w3f[4], w4f;
    #pragma unroll
    for (int f = 0; f < 8; f++)  w1f[f] = wf[f * 64 + lane];
    #pragma unroll
    for (int f = 0; f < 16; f++) w2f[f] = wf[(8 + f) * 64 + lane];
    #pragma unroll
    for (int f = 0; f < 4; f++)  w3f[f] = wf[(24 + f) * 64 + lane];
    w4f = wf[28 * 64 + lane];

    f32x4 bias2[4], bias3[2];
    #pragma unroll
    for (int t = 0; t < 4; t++) {
        int o = t * 16 + g * 4;
        bias2[t] = (f32x4){b2p[o], b2p[o + 1], b2p[o + 2], b2p[o + 3]};
    }
    #pragma unroll
    for (int t = 0; t < 2; t++) {
        int o = t * 16 + g * 4;
        bias3[t] = (f32x4){b3p[o], b3p[o + 1], b3p[o + 2], b3p[o + 3]};
    }
    float b4v = b4p[0];

    int base = (blockIdx.x * 4 + wv) * 512;

    for (int it = 0; it < 8; ++it) {
        // ---- all-lane coalesced input load: one element per lane ----
        int e = base + it * 64 + lane;
        const float* hp; int bd;
        if (e < 40960) {
            int e2 = (e < 20480) ? e : e - 20480;
            int b = e2 / 1280; int r = e2 - b * 1280;
            int n = r >> 8, d = r & 255;
            const float* srcp = (e < 20480) ? sup : supn;
            hp = srcp + ((b * 5 + n) * 2) * 256 + d;
            bd = b * 256 + d;
        } else {
            int e2 = e - 40960;
            int b = e2 >> 16, r = e2 & 65535, m = r >> 8, d = r & 255;
            hp = (m < 128) ? (qry + ((b * 128 + m) * 2) * 256 + d)
                           : (neg + ((b * 128 + (m - 128)) * 2) * 256 + d);
            bd = b * 256 + d;
        }
        float x0 = hp[0], x2 = hp[256], x1 = wsRel[bd];
        stage[wv][lane] = make_uint2(pkrz(x0, x1), pkrz(x2, 1.0f));

        #pragma unroll
        for (int j = 0; j < 4; ++j) {
            // B1: k 0..3 = (head, rel, tail, 1.0), conflict-free b64 read
            U8 b1; b1.w[0] = 0u; b1.w[1] = 0u; b1.w[2] = 0u; b1.w[3] = 0u;
            if (g == 0) {
                uint2 s = stage[wv][j * 16 + col];
                b1.w[0] = s.x; b1.w[1] = s.y;
            }

            // L1: 128 outs = 8 tiles
            f32x4 c1[8];
            #pragma unroll
            for (int t = 0; t < 8; t++) c1[t] = MFMA16(w1f[t], b1.h, zero4);

            // relu+pack directly into L2 B-fragments (channel-permuted weights)
            U8 b2f[4];
            #pragma unroll
            for (int kk = 0; kk < 4; kk++) {
                b2f[kk].w[0] = pkrelu(c1[2 * kk][0],     c1[2 * kk][1]);
                b2f[kk].w[1] = pkrelu(c1[2 * kk][2],     c1[2 * kk][3]);
                b2f[kk].w[2] = pkrelu(c1[2 * kk + 1][0], c1[2 * kk + 1][1]);
                b2f[kk].w[3] = pkrelu(c1[2 * kk + 1][2], c1[2 * kk + 1][3]);
            }

            // L2: 64 outs = 4 tiles, K=128
            f32x4 c2[4];
            #pragma unroll
            for (int t = 0; t < 4; t++) {
                f32x4 c = bias2[t];
                #pragma unroll
                for (int kk = 0; kk < 4; kk++) c = MFMA16(w2f[t * 4 + kk], b2f[kk].h, c);
                c2[t] = c;
            }

            U8 b3f[2];
            #pragma unroll
            for (int kk = 0; kk < 2; kk++) {
                b3f[kk].w[0] = pkrelu(c2[2 * kk][0],     c2[2 * kk][1]);
                b3f[kk].w[1] = pkrelu(c2[2 * kk][2],     c2[2 * kk][3]);
                b3f[kk].w[2] = pkrelu(c2[2 * kk + 1][0], c2[2 * kk + 1][1]);
                b3f[kk].w[3] = pkrelu(c2[2 * kk + 1][2], c2[2 * kk + 1][3]);
            }

            // L3: 32 outs = 2 tiles, K=64
            f32x4 c3[2];
            #pragma unroll
            for (int t = 0; t < 2; t++) {
                f32x4 c = bias3[t];
                #pragma unroll
                for (int kk = 0; kk < 2; kk++) c = MFMA16(w3f[t * 2 + kk], b3f[kk].h, c);
                c3[t] = c;
            }

            U8 b4f;
            b4f.w[0] = pkrelu(c3[0][0], c3[0][1]);
            b4f.w[1] = pkrelu(c3[0][2], c3[0][3]);
            b4f.w[2] = pkrelu(c3[1][0], c3[1][1]);
            b4f.w[3] = pkrelu(c3[1][2], c3[1][3]);

            // L4: 1 out
            f32x4 c4 = MFMA16(w4f, b4f.h, zero4);
            if (lane < 16) wsY[base + it * 64 + j * 16 + lane] = c4[0] + b4v;
        }
    }
}

// ---------------- proto / sneg means ----------------
__global__ void k_means(float* __restrict__ ws)
{
    int idx = blockIdx.x * 256 + threadIdx.x;   // 4096 = (b,d)
    int b = idx >> 8, d = idx & 255;
    const float* y = ws + OFF_Y;
    float sp = 0.f, sn = 0.f;
    #pragma unroll
    for (int n = 0; n < 5; n++) {
        sp += y[b * 1280 + n * 256 + d];
        sn += y[20480 + b * 1280 + n * 256 + d];
    }
    ws[OFF_PROTO + idx] = sp * 0.2f;
    ws[OFF_SNEG + idx] = sn * 0.2f;
}

// ---------------- scores: one wave per (b,m) row ----------------
__global__ __launch_bounds__(256) void k_scores(float* __restrict__ ws, float* __restrict__ out)
{
    int row = blockIdx.x * 4 + (threadIdx.x >> 6);   // 0..4095
    int lane = threadIdx.x & 63;
    int b = row >> 8, m = row & 255;
    const float* q = ws + OFF_Y + 40960 + row * 256;
    float q0 = q[lane], q1 = q[lane + 64], q2 = q[lane + 128], q3 = q[lane + 192];

    float s[17];
    #pragma unroll
    for (int c = 0; c < 16; c++) {
        const float* p = ws + OFF_PROTO + c * 256;
        float d0 = q0 - p[lane], d1 = q1 - p[lane + 64];
        float d2 = q2 - p[lane + 128], d3 = q3 - p[lane + 192];
        s[c] = d0 * d0 + d1 * d1 + d2 * d2 + d3 * d3;
    }
    {
        const float* p = ws + OFF_SNEG + b * 256;
        float d0 = q0 - p[lane], d1 = q1 - p[lane + 64];
        float d2 = q2 - p[lane + 128], d3 = q3 - p[lane + 192];
        s[16] = d0 * d0 + d1 * d1 + d2 * d2 + d3 * d3;
    }
    #pragma unroll
    for (int off = 32; off > 0; off >>= 1) {
        #pragma unroll
        for (int c = 0; c < 17; c++) s[c] += __shfl_xor(s[c], off, 64);
    }
    float sumd = 0.f, selfd = 0.f;
    #pragma unroll
    for (int c = 0; c < 16; c++) {
        float dc = sqrtf(s[c]);
        sumd += dc;
        if (c == b) selfd = dc;
    }
    float qpos = -selfd;
    float qneg = -sqrtf(s[16]);
    float relation = -(sumd - selfd) * (1.f / 15.f);
    float delta = qpos - qneg - 0.3f * relation;

    if (lane == 0) {
        out[2 * row] = qpos;
        out[2 * row + 1] = qneg;
        out[8192 + row] = (m < 128) ? 0.f : 1.f;
        float* sums = ws + OFF_SUMS;
        if (m < 128) {
            out[12288 + b * 128 + m] = delta;
            atomicAdd(&sums[0], qpos);
            atomicAdd(&sums[1], qneg);
        } else {
            out[14336 + b * 128 + (m - 128)] = delta;
        }
    }
}

// ---------------- delta_loss finisher ----------------
__global__ void k_final(const float* __restrict__ ws, float* __restrict__ out)
{
    if (threadIdx.x == 0) {
        float v = (ws[OFF_SUMS] - ws[OFF_SUMS + 1]) * (1.f / 2048.f) + 1.f;
        out[16384] = fmaxf(v, 0.f);
    }
}

extern "C" void kernel_launch(void* const* d_in, const int* in_sizes, int n_in,
                              void* d_out, int out_size, void* d_ws, size_t ws_size,
                              hipStream_t stream)
{
    const float* sup  = (const float*)d_in[0];
    const float* supn = (const float*)d_in[1];
    const float* qry  = (const float*)d_in[2];
    const float* neg  = (const float*)d_in[3];
    const float* w1   = (const float*)d_in[4];
    const float* b1   = (const float*)d_in[5];
    const float* w2   = (const float*)d_in[6];
    const float* b2   = (const float*)d_in[7];
    const float* w3   = (const float*)d_in[8];
    const float* b3   = (const float*)d_in[9];
    const float* w4   = (const float*)d_in[10];
    const float* b4   = (const float*)d_in[11];
    float* ws  = (float*)d_ws;
    float* out = (float*)d_out;

    (void)hipMemsetAsync(ws + OFF_SUMS, 0, 2 * sizeof(float), stream);
    k_prep  <<<17,   256, 0, stream>>>(sup, supn, w1, b1, w2, w3, w4, ws);
    k_main  <<<532,  256, 0, stream>>>(sup, supn, qry, neg, b2, b3, b4, ws);
    k_means <<<16,   256, 0, stream>>>(ws);
    k_scores<<<1024, 256, 0, stream>>>(ws, out);
    k_final <<<1,    64,  0, stream>>>(ws, out);
}

// Round 6
// 140.825 us; speedup vs baseline: 1.4761x; 1.4386x over previous
//
#include <hip/hip_runtime.h>
#include <hip/hip_bf16.h>

typedef _Float16 f16;
typedef f16 f16x8 __attribute__((ext_vector_type(8)));
typedef float f32x4 __attribute__((ext_vector_type(4)));
typedef unsigned int u32;

#define MFMA16(a, b, c) __builtin_amdgcn_mfma_f32_16x16x32_f16((a), (b), (c), 0, 0, 0)

__device__ __forceinline__ u32 pkrz(float a, float b) {
    auto r = __builtin_amdgcn_cvt_pkrtz(a, b);   // __fp16 ext_vector(2)
    return __builtin_bit_cast(u32, r);
}
__device__ __forceinline__ u32 pkrelu(float a, float b) {
    return pkrz(fmaxf(a, 0.f), fmaxf(b, 0.f));
}

union U8 { f16x8 h; u32 w[4]; };

// ---- ws layout (float offsets) ----
#define OFF_REL    0          // 4096 floats: rel[b*256+d]
#define OFF_Y      4096       // 1,089,536 floats: [spt_pos 20480][spt_neg 20480][qry 1048576]
#define OFF_PROTO  1093632    // 4096
#define OFF_SNEG   1097728    // 4096
#define OFF_W      1101828    // f16 region: 29 frags * 64 lanes * 8 halves

// ---------------- prep: rel + weight fragment packing ----------------
// Hidden-channel permutation: B-position (kk,g,i) holds C-slot
// (2kk + (i>>2))*16 + g*4 + (i&3) of the previous layer, so the layer
// transition is pure in-register relu+pack (no LDS / shuffles).
__global__ void k_prep(const float* __restrict__ sup, const float* __restrict__ supn,
                       const float* __restrict__ w1, const float* __restrict__ b1,
                       const float* __restrict__ w2, const float* __restrict__ w3,
                       const float* __restrict__ w4, float* __restrict__ ws)
{
    int tid = threadIdx.x;
    if (blockIdx.x < 16) {
        int idx = blockIdx.x * 256 + tid;     // (b,d)
        int b = idx >> 8, d = idx & 255;
        float acc = 0.f;
        #pragma unroll
        for (int n = 0; n < 5; n++) {
            const float* base = sup + ((b * 5 + n) * 2) * 256 + d;
            acc += base[256] - base[0];
        }
        ws[OFF_REL + idx] = acc * 0.2f;
    } else {
        f16* wf = (f16*)(ws + OFF_W);
        for (int id = tid; id < 29 * 64; id += 256) {
            int frag = id >> 6, lane = id & 63;
            int g = lane >> 4, cr = lane & 15, kb = g * 8;
            float vals[8];
            if (frag < 8) {                       // L1: W1 (128x3) + b1 folded at k==3
                int out = frag * 16 + cr;
                #pragma unroll
                for (int i = 0; i < 8; i++) {
                    int k = kb + i;
                    vals[i] = (k < 3) ? w1[out * 3 + k] : (k == 3 ? b1[out] : 0.f);
                }
            } else if (frag < 24) {               // L2: W2 (64x128), permuted input cols
                int f = frag - 8; int t = f >> 2, kk = f & 3; int out = t * 16 + cr;
                #pragma unroll
                for (int i = 0; i < 8; i++) {
                    int u = (2 * kk + (i >> 2)) * 16 + g * 4 + (i & 3);
                    vals[i] = w2[out * 128 + u];
                }
            } else if (frag < 28) {               // L3: W3 (32x64), permuted input cols
                int f = frag - 24; int t = f >> 1, kk = f & 1; int out = t * 16 + cr;
                #pragma unroll
                for (int i = 0; i < 8; i++) {
                    int u = (2 * kk + (i >> 2)) * 16 + g * 4 + (i & 3);
                    vals[i] = w3[out * 64 + u];
                }
            } else {                              // L4: W4 (1x32), permuted, rows 1..15 zero
                #pragma unroll
                for (int i = 0; i < 8; i++) {
                    int u = (i >> 2) * 16 + g * 4 + (i & 3);
                    vals[i] = (cr == 0) ? w4[u] : 0.f;
                }
            }
            #pragma unroll
            for (int i = 0; i < 8; i++) wf[id * 8 + i] = (f16)vals[i];
        }
    }
}

// ---------------- main fused MLP: all-register layer chain ----------------
// 1064 blocks x 4 waves x 4 iters x 64 elems = 1,089,536
__global__ __launch_bounds__(256) void k_main(
    const float* __restrict__ sup, const float* __restrict__ supn,
    const float* __restrict__ qry, const float* __restrict__ neg,
    const float* __restrict__ b2p, const float* __restrict__ b3p,
    const float* __restrict__ b4p, float* __restrict__ ws)
{
    __shared__ uint2 stage[4][64];                 // 2 KB/block
    const float* wsRel = ws + OFF_REL;
    float* wsY = ws + OFF_Y;
    const f16x8* wf = (const f16x8*)(ws + OFF_W);

    int tid = threadIdx.x, wv = tid >> 6, lane = tid & 63;
    int g = lane >> 4, col = lane & 15;
    const f32x4 zero4 = {0.f, 0.f, 0.f, 0.f};

    // register-resident weight fragments (reused over 4*4 tiles)
    f16x8 w1f[8], w2f[16], w3f[4], w4f;
    #pragma unroll
    for (int f = 0; f < 8; f++)  w1f[f] = wf[f * 64 + lane];
    #pragma unroll
    for (int f = 0; f < 16; f++) w2f[f] = wf[(8 + f) * 64 + lane];
    #pragma unroll
    for (int f = 0; f < 4; f++)  w3f[f] = wf[(24 + f) * 64 + lane];
    w4f = wf[28 * 64 + lane];

    f32x4 bias2[4], bias3[2];
    #pragma unroll
    for (int t = 0; t < 4; t++) {
        int o = t * 16 + g * 4;
        bias2[t] = (f32x4){b2p[o], b2p[o + 1], b2p[o + 2], b2p[o + 3]};
    }
    #pragma unroll
    for (int t = 0; t < 2; t++) {
        int o = t * 16 + g * 4;
        bias3[t] = (f32x4){b3p[o], b3p[o + 1], b3p[o + 2], b3p[o + 3]};
    }
    float b4v = b4p[0];

    int base = (blockIdx.x * 4 + wv) * 256;

    for (int it = 0; it < 4; ++it) {
        // ---- all-lane coalesced input load: one element per lane ----
        int e = base + it * 64 + lane;
        const float* hp; int bd;
        if (e < 40960) {
            int e2 = (e < 20480) ? e : e - 20480;
            int b = e2 / 1280; int r = e2 - b * 1280;
            int n = r >> 8, d = r & 255;
            const float* srcp = (e < 20480) ? sup : supn;
            hp = srcp + ((b * 5 + n) * 2) * 256 + d;
            bd = b * 256 + d;
        } else {
            int e2 = e - 40960;
            int b = e2 >> 16, r = e2 & 65535, m = r >> 8, d = r & 255;
            hp = (m < 128) ? (qry + ((b * 128 + m) * 2) * 256 + d)
                           : (neg + ((b * 128 + (m - 128)) * 2) * 256 + d);
            bd = b * 256 + d;
        }
        float x0 = hp[0], x2 = hp[256], x1 = wsRel[bd];
        stage[wv][lane] = make_uint2(pkrz(x0, x1), pkrz(x2, 1.0f));

        #pragma unroll
        for (int j = 0; j < 4; ++j) {
            // B1: k 0..3 = (head, rel, tail, 1.0), conflict-free b64 read
            U8 b1; b1.w[0] = 0u; b1.w[1] = 0u; b1.w[2] = 0u; b1.w[3] = 0u;
            if (g == 0) {
                uint2 s = stage[wv][j * 16 + col];
                b1.w[0] = s.x; b1.w[1] = s.y;
            }

            // L1: 128 outs = 8 tiles
            f32x4 c1[8];
            #pragma unroll
            for (int t = 0; t < 8; t++) c1[t] = MFMA16(w1f[t], b1.h, zero4);

            // relu+pack directly into L2 B-fragments (channel-permuted weights)
            U8 b2f[4];
            #pragma unroll
            for (int kk = 0; kk < 4; kk++) {
                b2f[kk].w[0] = pkrelu(c1[2 * kk][0],     c1[2 * kk][1]);
                b2f[kk].w[1] = pkrelu(c1[2 * kk][2],     c1[2 * kk][3]);
                b2f[kk].w[2] = pkrelu(c1[2 * kk + 1][0], c1[2 * kk + 1][1]);
                b2f[kk].w[3] = pkrelu(c1[2 * kk + 1][2], c1[2 * kk + 1][3]);
            }

            // L2: 64 outs = 4 tiles, K=128
            f32x4 c2[4];
            #pragma unroll
            for (int t = 0; t < 4; t++) {
                f32x4 c = bias2[t];
                #pragma unroll
                for (int kk = 0; kk < 4; kk++) c = MFMA16(w2f[t * 4 + kk], b2f[kk].h, c);
                c2[t] = c;
            }

            U8 b3f[2];
            #pragma unroll
            for (int kk = 0; kk < 2; kk++) {
                b3f[kk].w[0] = pkrelu(c2[2 * kk][0],     c2[2 * kk][1]);
                b3f[kk].w[1] = pkrelu(c2[2 * kk][2],     c2[2 * kk][3]);
                b3f[kk].w[2] = pkrelu(c2[2 * kk + 1][0], c2[2 * kk + 1][1]);
                b3f[kk].w[3] = pkrelu(c2[2 * kk + 1][2], c2[2 * kk + 1][3]);
            }

            // L3: 32 outs = 2 tiles, K=64
            f32x4 c3[2];
            #pragma unroll
            for (int t = 0; t < 2; t++) {
                f32x4 c = bias3[t];
                #pragma unroll
                for (int kk = 0; kk < 2; kk++) c = MFMA16(w3f[t * 2 + kk], b3f[kk].h, c);
                c3[t] = c;
            }

            U8 b4f;
            b4f.w[0] = pkrelu(c3[0][0], c3[0][1]);
            b4f.w[1] = pkrelu(c3[0][2], c3[0][3]);
            b4f.w[2] = pkrelu(c3[1][0], c3[1][1]);
            b4f.w[3] = pkrelu(c3[1][2], c3[1][3]);

            // L4: 1 out
            f32x4 c4 = MFMA16(w4f, b4f.h, zero4);
            if (lane < 16) wsY[base + it * 64 + j * 16 + lane] = c4[0] + b4v;
        }
    }
}

// ---------------- proto / sneg means ----------------
__global__ void k_means(float* __restrict__ ws)
{
    int idx = blockIdx.x * 256 + threadIdx.x;   // 4096 = (b,d)
    int b = idx >> 8, d = idx & 255;
    const float* y = ws + OFF_Y;
    float sp = 0.f, sn = 0.f;
    #pragma unroll
    for (int n = 0; n < 5; n++) {
        sp += y[b * 1280 + n * 256 + d];
        sn += y[20480 + b * 1280 + n * 256 + d];
    }
    ws[OFF_PROTO + idx] = sp * 0.2f;
    ws[OFF_SNEG + idx] = sn * 0.2f;
}

// ---------------- scores: one wave per (b,m) row (no atomics) ----------------
__global__ __launch_bounds__(256) void k_scores(float* __restrict__ ws, float* __restrict__ out)
{
    int row = blockIdx.x * 4 + (threadIdx.x >> 6);   // 0..4095
    int lane = threadIdx.x & 63;
    int b = row >> 8, m = row & 255;
    const float* q = ws + OFF_Y + 40960 + row * 256;
    float q0 = q[lane], q1 = q[lane + 64], q2 = q[lane + 128], q3 = q[lane + 192];

    float s[17];
    #pragma unroll
    for (int c = 0; c < 16; c++) {
        const float* p = ws + OFF_PROTO + c * 256;
        float d0 = q0 - p[lane], d1 = q1 - p[lane + 64];
        float d2 = q2 - p[lane + 128], d3 = q3 - p[lane + 192];
        s[c] = d0 * d0 + d1 * d1 + d2 * d2 + d3 * d3;
    }
    {
        const float* p = ws + OFF_SNEG + b * 256;
        float d0 = q0 - p[lane], d1 = q1 - p[lane + 64];
        float d2 = q2 - p[lane + 128], d3 = q3 - p[lane + 192];
        s[16] = d0 * d0 + d1 * d1 + d2 * d2 + d3 * d3;
    }
    #pragma unroll
    for (int off = 32; off > 0; off >>= 1) {
        #pragma unroll
        for (int c = 0; c < 17; c++) s[c] += __shfl_xor(s[c], off, 64);
    }
    float sumd = 0.f, selfd = 0.f;
    #pragma unroll
    for (int c = 0; c < 16; c++) {
        float dc = sqrtf(s[c]);
        sumd += dc;
        if (c == b) selfd = dc;
    }
    float qpos = -selfd;
    float qneg = -sqrtf(s[16]);
    float relation = -(sumd - selfd) * (1.f / 15.f);
    float delta = qpos - qneg - 0.3f * relation;

    if (lane == 0) {
        out[2 * row] = qpos;
        out[2 * row + 1] = qneg;
        out[8192 + row] = (m < 128) ? 0.f : 1.f;
        if (m < 128) out[12288 + b * 128 + m] = delta;
        else         out[14336 + b * 128 + (m - 128)] = delta;
    }
}

// ---------------- delta_loss finisher: reduce over out[] (no atomics) ----------------
__global__ __launch_bounds__(256) void k_final(float* __restrict__ out)
{
    __shared__ float red[2][256];
    int t = threadIdx.x;
    float sp = 0.f, sn = 0.f;
    #pragma unroll
    for (int i = 0; i < 8; i++) {
        int idx = t + 256 * i;            // 2048 (b, m<128) rows
        int b = idx >> 7, m = idx & 127;
        int row = b * 256 + m;
        sp += out[2 * row];
        sn += out[2 * row + 1];
    }
    red[0][t] = sp; red[1][t] = sn;
    __syncthreads();
    #pragma unroll
    for (int off = 128; off > 0; off >>= 1) {
        if (t < off) { red[0][t] += red[0][t + off]; red[1][t] += red[1][t + off]; }
        __syncthreads();
    }
    if (t == 0) {
        float v = (red[0][0] - red[1][0]) * (1.f / 2048.f) + 1.f;
        out[16384] = fmaxf(v, 0.f);
    }
}

extern "C" void kernel_launch(void* const* d_in, const int* in_sizes, int n_in,
                              void* d_out, int out_size, void* d_ws, size_t ws_size,
                              hipStream_t stream)
{
    const float* sup  = (const float*)d_in[0];
    const float* supn = (const float*)d_in[1];
    const float* qry  = (const float*)d_in[2];
    const float* neg  = (const float*)d_in[3];
    const float* w1   = (const float*)d_in[4];
    const float* b1   = (const float*)d_in[5];
    const float* w2   = (const float*)d_in[6];
    const float* b2   = (const float*)d_in[7];
    const float* w3   = (const float*)d_in[8];
    const float* b3   = (const float*)d_in[9];
    const float* w4   = (const float*)d_in[10];
    const float* b4   = (const float*)d_in[11];
    float* ws  = (float*)d_ws;
    float* out = (float*)d_out;

    k_prep  <<<17,   256, 0, stream>>>(sup, supn, w1, b1, w2, w3, w4, ws);
    k_main  <<<1064, 256, 0, stream>>>(sup, supn, qry, neg, b2, b3, b4, ws);
    k_means <<<16,   256, 0, stream>>>(ws);
    k_scores<<<1024, 256, 0, stream>>>(ws, out);
    k_final <<<1,    256, 0, stream>>>(out);
}

// Round 9
// 137.204 us; speedup vs baseline: 1.5151x; 1.0264x over previous
//
#include <hip/hip_runtime.h>
#include <hip/hip_bf16.h>

typedef _Float16 f16;
typedef f16 f16x8 __attribute__((ext_vector_type(8)));
typedef f16 f16x2 __attribute__((ext_vector_type(2)));
typedef float f32x4 __attribute__((ext_vector_type(4)));
typedef unsigned int u32;

#define MFMA16(a, b, c) __builtin_amdgcn_mfma_f32_16x16x32_f16((a), (b), (c), 0, 0, 0)

__device__ __forceinline__ u32 pkrz(float a, float b) {
    auto r = __builtin_amdgcn_cvt_pkrtz(a, b);   // __fp16 ext_vector(2)
    return __builtin_bit_cast(u32, r);
}
// packed relu on 2xf16 (v_pk_max_f16); exact vs relu-then-cvt since RTZ is monotone
__device__ __forceinline__ u32 pkmax0(u32 x) {
    f16x2 h = __builtin_bit_cast(f16x2, x);
    f16x2 z = {(f16)0.f, (f16)0.f};
    f16x2 m = __builtin_elementwise_max(h, z);
    return __builtin_bit_cast(u32, m);
}
__device__ __forceinline__ u32 pkrelu(float a, float b) {
    return pkmax0(pkrz(a, b));
}

union U8 { f16x8 h; u32 w[4]; };

// ---- ws layout (float offsets) ----
#define OFF_REL    0          // 4096 floats: rel[b*256+d]
#define OFF_Y      4096       // 1,089,536 floats: [spt_pos 20480][spt_neg 20480][qry 1048576]
#define OFF_PROTO  1093632    // 4096
#define OFF_SNEG   1097728    // 4096
#define OFF_W      1101828    // f16 region: 29 frags * 64 lanes * 8 halves

// ---------------- prep: rel + weight fragment packing ----------------
// Hidden-channel permutation: B-position (kk,g,i) holds C-slot
// (2kk + (i>>2))*16 + g*4 + (i&3) of the previous layer, so the layer
// transition is pure in-register relu+pack (no LDS / shuffles).
__global__ void k_prep(const float* __restrict__ sup, const float* __restrict__ supn,
                       const float* __restrict__ w1, const float* __restrict__ b1,
                       const float* __restrict__ w2, const float* __restrict__ w3,
                       const float* __restrict__ w4, float* __restrict__ ws)
{
    int tid = threadIdx.x;
    if (blockIdx.x < 16) {
        int idx = blockIdx.x * 256 + tid;     // (b,d)
        int b = idx >> 8, d = idx & 255;
        float acc = 0.f;
        #pragma unroll
        for (int n = 0; n < 5; n++) {
            const float* base = sup + ((b * 5 + n) * 2) * 256 + d;
            acc += base[256] - base[0];
        }
        ws[OFF_REL + idx] = acc * 0.2f;
    } else {
        f16* wf = (f16*)(ws + OFF_W);
        for (int id = tid; id < 29 * 64; id += 256) {
            int frag = id >> 6, lane = id & 63;
            int g = lane >> 4, cr = lane & 15, kb = g * 8;
            float vals[8];
            if (frag < 8) {                       // L1: W1 (128x3) + b1 folded at k==3
                int out = frag * 16 + cr;
                #pragma unroll
                for (int i = 0; i < 8; i++) {
                    int k = kb + i;
                    vals[i] = (k < 3) ? w1[out * 3 + k] : (k == 3 ? b1[out] : 0.f);
                }
            } else if (frag < 24) {               // L2: W2 (64x128), permuted input cols
                int f = frag - 8; int t = f >> 2, kk = f & 3; int out = t * 16 + cr;
                #pragma unroll
                for (int i = 0; i < 8; i++) {
                    int u = (2 * kk + (i >> 2)) * 16 + g * 4 + (i & 3);
                    vals[i] = w2[out * 128 + u];
                }
            } else if (frag < 28) {               // L3: W3 (32x64), permuted input cols
                int f = frag - 24; int t = f >> 1, kk = f & 1; int out = t * 16 + cr;
                #pragma unroll
                for (int i = 0; i < 8; i++) {
                    int u = (2 * kk + (i >> 2)) * 16 + g * 4 + (i & 3);
                    vals[i] = w3[out * 64 + u];
                }
            } else {                              // L4: W4 (1x32), permuted, rows 1..15 zero
                #pragma unroll
                for (int i = 0; i < 8; i++) {
                    int u = (i >> 2) * 16 + g * 4 + (i & 3);
                    vals[i] = (cr == 0) ? w4[u] : 0.f;
                }
            }
            #pragma unroll
            for (int i = 0; i < 8; i++) wf[id * 8 + i] = (f16)vals[i];
        }
    }
}

// ---------------- main fused MLP: register chain, L2 weights in LDS ----------------
// 1064 blocks x 4 waves x 4 iters x 64 elems = 1,089,536
__global__ __launch_bounds__(256, 3) void k_main(
    const float* __restrict__ sup, const float* __restrict__ supn,
    const float* __restrict__ qry, const float* __restrict__ neg,
    const float* __restrict__ b2p, const float* __restrict__ b3p,
    const float* __restrict__ b4p, float* __restrict__ ws)
{
    __shared__ __align__(16) f16x8 w2lds[16 * 64];   // 16 KB: L2 frags, shared by 4 waves
    __shared__ uint2 stage[4][64];                   // 2 KB
    const float* wsRel = ws + OFF_REL;
    float* wsY = ws + OFF_Y;
    const f16x8* wf = (const f16x8*)(ws + OFF_W);

    int tid = threadIdx.x, wv = tid >> 6, lane = tid & 63;
    int g = lane >> 4, col = lane & 15;
    const f32x4 zero4 = {0.f, 0.f, 0.f, 0.f};

    // block-cooperative copy of L2 weight frags (frags 8..23) into LDS
    #pragma unroll
    for (int i = 0; i < 4; i++) {
        int idx = tid + 256 * i;                     // 0..1023
        w2lds[idx] = wf[8 * 64 + idx];
    }

    // small frag sets stay register-resident (13 frags = 52 regs)
    f16x8 w1f[8], w3f[4], w4f;
    #pragma unroll
    for (int f = 0; f < 8; f++)  w1f[f] = wf[f * 64 + lane];
    #pragma unroll
    for (int f = 0; f < 4; f++)  w3f[f] = wf[(24 + f) * 64 + lane];
    w4f = wf[28 * 64 + lane];

    f32x4 bias2[4], bias3[2];
    #pragma unroll
    for (int t = 0; t < 4; t++) {
        int o = t * 16 + g * 4;
        bias2[t] = (f32x4){b2p[o], b2p[o + 1], b2p[o + 2], b2p[o + 3]};
    }
    #pragma unroll
    for (int t = 0; t < 2; t++) {
        int o = t * 16 + g * 4;
        bias3[t] = (f32x4){b3p[o], b3p[o + 1], b3p[o + 2], b3p[o + 3]};
    }
    float b4v = b4p[0];

    __syncthreads();                                  // w2lds ready

    int base = (blockIdx.x * 4 + wv) * 256;

    for (int it = 0; it < 4; ++it) {
        // ---- all-lane coalesced input load: one element per lane ----
        int e = base + it * 64 + lane;
        const float* hp; int bd;
        if (e < 40960) {
            int e2 = (e < 20480) ? e : e - 20480;
            int b = e2 / 1280; int r = e2 - b * 1280;
            int n = r >> 8, d = r & 255;
            const float* srcp = (e < 20480) ? sup : supn;
            hp = srcp + ((b * 5 + n) * 2) * 256 + d;
            bd = b * 256 + d;
        } else {
            int e2 = e - 40960;
            int b = e2 >> 16, r = e2 & 65535, m = r >> 8, d = r & 255;
            hp = (m < 128) ? (qry + ((b * 128 + m) * 2) * 256 + d)
                           : (neg + ((b * 128 + (m - 128)) * 2) * 256 + d);
            bd = b * 256 + d;
        }
        float x0 = hp[0], x2 = hp[256], x1 = wsRel[bd];
        stage[wv][lane] = make_uint2(pkrz(x0, x1), pkrz(x2, 1.0f));

        #pragma unroll
        for (int j = 0; j < 4; ++j) {
            // B1: k 0..3 = (head, rel, tail, 1.0), conflict-free b64 read
            U8 b1; b1.w[0] = 0u; b1.w[1] = 0u; b1.w[2] = 0u; b1.w[3] = 0u;
            if (g == 0) {
                uint2 s = stage[wv][j * 16 + col];
                b1.w[0] = s.x; b1.w[1] = s.y;
            }

            // L1: 128 outs = 8 tiles
            f32x4 c1[8];
            #pragma unroll
            for (int t = 0; t < 8; t++) c1[t] = MFMA16(w1f[t], b1.h, zero4);

            // relu+pack directly into L2 B-fragments (channel-permuted weights)
            U8 b2f[4];
            #pragma unroll
            for (int kk = 0; kk < 4; kk++) {
                b2f[kk].w[0] = pkrelu(c1[2 * kk][0],     c1[2 * kk][1]);
                b2f[kk].w[1] = pkrelu(c1[2 * kk][2],     c1[2 * kk][3]);
                b2f[kk].w[2] = pkrelu(c1[2 * kk + 1][0], c1[2 * kk + 1][1]);
                b2f[kk].w[3] = pkrelu(c1[2 * kk + 1][2], c1[2 * kk + 1][3]);
            }

            // L2: 64 outs = 4 tiles, K=128; weights stream from LDS
            f32x4 c2[4];
            #pragma unroll
            for (int t = 0; t < 4; t++) {
                f32x4 c = bias2[t];
                #pragma unroll
                for (int kk = 0; kk < 4; kk++)
                    c = MFMA16(w2lds[(t * 4 + kk) * 64 + lane], b2f[kk].h, c);
                c2[t] = c;
            }

            U8 b3f[2];
            #pragma unroll
            for (int kk = 0; kk < 2; kk++) {
                b3f[kk].w[0] = pkrelu(c2[2 * kk][0],     c2[2 * kk][1]);
                b3f[kk].w[1] = pkrelu(c2[2 * kk][2],     c2[2 * kk][3]);
                b3f[kk].w[2] = pkrelu(c2[2 * kk + 1][0], c2[2 * kk + 1][1]);
                b3f[kk].w[3] = pkrelu(c2[2 * kk + 1][2], c2[2 * kk + 1][3]);
            }

            // L3: 32 outs = 2 tiles, K=64
            f32x4 c3[2];
            #pragma unroll
            for (int t = 0; t < 2; t++) {
                f32x4 c = bias3[t];
                #pragma unroll
                for (int kk = 0; kk < 2; kk++) c = MFMA16(w3f[t * 2 + kk], b3f[kk].h, c);
                c3[t] = c;
            }

            U8 b4f;
            b4f.w[0] = pkrelu(c3[0][0], c3[0][1]);
            b4f.w[1] = pkrelu(c3[0][2], c3[0][3]);
            b4f.w[2] = pkrelu(c3[1][0], c3[1][1]);
            b4f.w[3] = pkrelu(c3[1][2], c3[1][3]);

            // L4: 1 out
            f32x4 c4 = MFMA16(w4f, b4f.h, zero4);
            if (lane < 16) wsY[base + it * 64 + j * 16 + lane] = c4[0] + b4v;
        }
    }
}

// ---------------- proto / sneg means ----------------
__global__ void k_means(float* __restrict__ ws)
{
    int idx = blockIdx.x * 256 + threadIdx.x;   // 4096 = (b,d)
    int b = idx >> 8, d = idx & 255;
    const float* y = ws + OFF_Y;
    float sp = 0.f, sn = 0.f;
    #pragma unroll
    for (int n = 0; n < 5; n++) {
        sp += y[b * 1280 + n * 256 + d];
        sn += y[20480 + b * 1280 + n * 256 + d];
    }
    ws[OFF_PROTO + idx] = sp * 0.2f;
    ws[OFF_SNEG + idx] = sn * 0.2f;
}

// ---------------- scores: one wave per (b,m) row (no atomics) ----------------
__global__ __launch_bounds__(256) void k_scores(float* __restrict__ ws, float* __restrict__ out)
{
    int row = blockIdx.x * 4 + (threadIdx.x >> 6);   // 0..4095
    int lane = threadIdx.x & 63;
    int b = row >> 8, m = row & 255;
    const float* q = ws + OFF_Y + 40960 + row * 256;
    float q0 = q[lane], q1 = q[lane + 64], q2 = q[lane + 128], q3 = q[lane + 192];

    float s[17];
    #pragma unroll
    for (int c = 0; c < 16; c++) {
        const float* p = ws + OFF_PROTO + c * 256;
        float d0 = q0 - p[lane], d1 = q1 - p[lane + 64];
        float d2 = q2 - p[lane + 128], d3 = q3 - p[lane + 192];
        s[c] = d0 * d0 + d1 * d1 + d2 * d2 + d3 * d3;
    }
    {
        const float* p = ws + OFF_SNEG + b * 256;
        float d0 = q0 - p[lane], d1 = q1 - p[lane + 64];
        float d2 = q2 - p[lane + 128], d3 = q3 - p[lane + 192];
        s[16] = d0 * d0 + d1 * d1 + d2 * d2 + d3 * d3;
    }
    #pragma unroll
    for (int off = 32; off > 0; off >>= 1) {
        #pragma unroll
        for (int c = 0; c < 17; c++) s[c] += __shfl_xor(s[c], off, 64);
    }
    float sumd = 0.f, selfd = 0.f;
    #pragma unroll
    for (int c = 0; c < 16; c++) {
        float dc = sqrtf(s[c]);
        sumd += dc;
        if (c == b) selfd = dc;
    }
    float qpos = -selfd;
    float qneg = -sqrtf(s[16]);
    float relation = -(sumd - selfd) * (1.f / 15.f);
    float delta = qpos - qneg - 0.3f * relation;

    if (lane == 0) {
        out[2 * row] = qpos;
        out[2 * row + 1] = qneg;
        out[8192 + row] = (m < 128) ? 0.f : 1.f;
        if (m < 128) out[12288 + b * 128 + m] = delta;
        else         out[14336 + b * 128 + (m - 128)] = delta;
    }
}

// ---------------- delta_loss finisher: reduce over out[] (no atomics) ----------------
__global__ __launch_bounds__(256) void k_final(float* __restrict__ out)
{
    __shared__ float red[2][256];
    int t = threadIdx.x;
    float sp = 0.f, sn = 0.f;
    #pragma unroll
    for (int i = 0; i < 8; i++) {
        int idx = t + 256 * i;            // 2048 (b, m<128) rows
        int b = idx >> 7, m = idx & 127;
        int row = b * 256 + m;
        sp += out[2 * row];
        sn += out[2 * row + 1];
    }
    red[0][t] = sp; red[1][t] = sn;
    __syncthreads();
    #pragma unroll
    for (int off = 128; off > 0; off >>= 1) {
        if (t < off) { red[0][t] += red[0][t + off]; red[1][t] += red[1][t + off]; }
        __syncthreads();
    }
    if (t == 0) {
        float v = (red[0][0] - red[1][0]) * (1.f / 2048.f) + 1.f;
        out[16384] = fmaxf(v, 0.f);
    }
}

extern "C" void kernel_launch(void* const* d_in, const int* in_sizes, int n_in,
                              void* d_out, int out_size, void* d_ws, size_t ws_size,
                              hipStream_t stream)
{
    const float* sup  = (const float*)d_in[0];
    const float* supn = (const float*)d_in[1];
    const float* qry  = (const float*)d_in[2];
    const float* neg  = (const float*)d_in[3];
    const float* w1   = (const float*)d_in[4];
    const float* b1   = (const float*)d_in[5];
    const float* w2   = (const float*)d_in[6];
    const float* b2   = (const float*)d_in[7];
    const float* w3   = (const float*)d_in[8];
    const float* b3   = (const float*)d_in[9];
    const float* w4   = (const float*)d_in[10];
    const float* b4   = (const float*)d_in[11];
    float* ws  = (float*)d_ws;
    float* out = (float*)d_out;

    k_prep  <<<17,   256, 0, stream>>>(sup, supn, w1, b1, w2, w3, w4, ws);
    k_main  <<<1064, 256, 0, stream>>>(sup, supn, qry, neg, b2, b3, b4, ws);
    k_means <<<16,   256, 0, stream>>>(ws);
    k_scores<<<1024, 256, 0, stream>>>(ws, out);
    k_final <<<1,    256, 0, stream>>>(out);
}

// Round 11
// 130.753 us; speedup vs baseline: 1.5899x; 1.0493x over previous
//
#include <hip/hip_runtime.h>
#include <hip/hip_bf16.h>

typedef _Float16 f16;
typedef f16 f16x8 __attribute__((ext_vector_type(8)));
typedef f16 f16x2 __attribute__((ext_vector_type(2)));
typedef float f32x4 __attribute__((ext_vector_type(4)));
typedef unsigned int u32;

#define MFMA16(a, b, c) __builtin_amdgcn_mfma_f32_16x16x32_f16((a), (b), (c), 0, 0, 0)

__device__ __forceinline__ u32 pkrz(float a, float b) {
    auto r = __builtin_amdgcn_cvt_pkrtz(a, b);
    return __builtin_bit_cast(u32, r);
}
__device__ __forceinline__ u32 pkmax0(u32 x) {
    f16x2 h = __builtin_bit_cast(f16x2, x);
    f16x2 z = {(f16)0.f, (f16)0.f};
    f16x2 m = __builtin_elementwise_max(h, z);
    return __builtin_bit_cast(u32, m);
}
__device__ __forceinline__ u32 pkrelu(float a, float b) {
    return pkmax0(pkrz(a, b));
}

union U8 { f16x8 h; u32 w[4]; };

// ---- ws layout (float offsets) ----
#define OFF_Y      4096       // 1,089,536 floats: [spt_pos 20480][spt_neg 20480][qry 1048576]

__device__ __forceinline__ int b_of(int e) {
    if (e < 20480) return e / 1280;
    if (e < 40960) return (e - 20480) / 1280;
    return (e - 40960) >> 16;
}

// ---------------- fused main: per-block prep + all-register MLP chain ----------------
// 1064 blocks x 4 waves x 4 iters x 64 elems = 1,089,536
// Hidden-channel permutation: B-position (kk,g,i) holds C-slot
// (2kk + (i>>2))*16 + g*4 + (i&3) of the previous layer -> layer transition is
// pure in-register relu+pack. L2 weights stream from LDS, one read per 2 chunks.
__global__ __launch_bounds__(256, 2) void k_main(
    const float* __restrict__ sup, const float* __restrict__ supn,
    const float* __restrict__ qry, const float* __restrict__ neg,
    const float* __restrict__ w1, const float* __restrict__ b1p,
    const float* __restrict__ w2, const float* __restrict__ w3,
    const float* __restrict__ w4, const float* __restrict__ b2p,
    const float* __restrict__ b3p, const float* __restrict__ b4p,
    float* __restrict__ ws)
{
    __shared__ __align__(16) f16x8 w2lds[16 * 64];   // 16 KB: L2 frags
    __shared__ __align__(16) f16x8 wpk[13 * 64];     // 13 KB: L1(0..7), L3(8..11), L4(12)
    __shared__ uint2 stage[4][64];                   // 2 KB
    __shared__ float relb[2][256];                   // 2 KB
    float* wsY = ws + OFF_Y;

    int tid = threadIdx.x, wv = tid >> 6, lane = tid & 63;
    int g = lane >> 4, col = lane & 15;
    const f32x4 zero4 = {0.f, 0.f, 0.f, 0.f};

    int blkbase = blockIdx.x * 1024;
    int rb0 = b_of(blkbase), rb1 = b_of(blkbase + 1023);

    // ---- per-block rel for the <=2 batch rows this block touches ----
    #pragma unroll
    for (int k = 0; k < 2; k++) {
        int bb = k ? rb1 : rb0;
        float acc = 0.f;
        #pragma unroll
        for (int n = 0; n < 5; n++) {
            const float* base = sup + ((bb * 5 + n) * 2) * 256 + tid;
            acc += base[256] - base[0];
        }
        relb[k][tid] = acc * 0.2f;
    }

    // ---- per-block W2 fragment packing into LDS (frag f: t=f>>2, kk=f&3) ----
    #pragma unroll
    for (int i = 0; i < 4; i++) {
        int id = tid + 256 * i;                      // 0..1023
        int f = id >> 6, ln = id & 63;
        int gg = ln >> 4, cr = ln & 15;
        int t = f >> 2, kk = f & 3, out = t * 16 + cr;
        U8 v;
        #pragma unroll
        for (int i2 = 0; i2 < 8; i2++) {
            int u = (2 * kk + (i2 >> 2)) * 16 + gg * 4 + (i2 & 3);
            v.h[i2] = (f16)w2[out * 128 + u];
        }
        w2lds[id] = v.h;
    }
    // ---- per-block W1/W3/W4 fragment packing ----
    for (int id = tid; id < 13 * 64; id += 256) {
        int fi = id >> 6, ln = id & 63;
        int gg = ln >> 4, cr = ln & 15, kb = gg * 8;
        U8 v;
        if (fi < 8) {                                 // L1 + b1 folded at k==3
            int out = fi * 16 + cr;
            #pragma unroll
            for (int i2 = 0; i2 < 8; i2++) {
                int k = kb + i2;
                v.h[i2] = (f16)((k < 3) ? w1[out * 3 + k] : (k == 3 ? b1p[out] : 0.f));
            }
        } else if (fi < 12) {                         // L3, permuted input cols
            int f = fi - 8; int t = f >> 1, kk = f & 1; int out = t * 16 + cr;
            #pragma unroll
            for (int i2 = 0; i2 < 8; i2++) {
                int u = (2 * kk + (i2 >> 2)) * 16 + gg * 4 + (i2 & 3);
                v.h[i2] = (f16)w3[out * 64 + u];
            }
        } else {                                      // L4, rows 1..15 zero
            #pragma unroll
            for (int i2 = 0; i2 < 8; i2++) {
                int u = (i2 >> 2) * 16 + gg * 4 + (i2 & 3);
                v.h[i2] = (f16)((cr == 0) ? w4[u] : 0.f);
            }
        }
        wpk[id] = v.h;
    }
    __syncthreads();

    // register frags for small layers
    f16x8 w1f[8], w3f[4], w4f;
    #pragma unroll
    for (int f = 0; f < 8; f++) w1f[f] = wpk[f * 64 + lane];
    #pragma unroll
    for (int f = 0; f < 4; f++) w3f[f] = wpk[(8 + f) * 64 + lane];
    w4f = wpk[12 * 64 + lane];

    f32x4 bias2[4], bias3[2];
    #pragma unroll
    for (int t = 0; t < 4; t++) {
        int o = t * 16 + g * 4;
        bias2[t] = (f32x4){b2p[o], b2p[o + 1], b2p[o + 2], b2p[o + 3]};
    }
    #pragma unroll
    for (int t = 0; t < 2; t++) {
        int o = t * 16 + g * 4;
        bias3[t] = (f32x4){b3p[o], b3p[o + 1], b3p[o + 2], b3p[o + 3]};
    }
    float b4v = b4p[0];

    int base = blkbase + wv * 256;

    for (int it = 0; it < 4; ++it) {
        // ---- all-lane coalesced input load: one element per lane ----
        int e = base + it * 64 + lane;
        const float* hp; int bb, dd;
        if (e < 40960) {
            int e2 = (e < 20480) ? e : e - 20480;
            bb = e2 / 1280; int r = e2 - bb * 1280;
            int n = r >> 8; dd = r & 255;
            const float* srcp = (e < 20480) ? sup : supn;
            hp = srcp + ((bb * 5 + n) * 2) * 256 + dd;
        } else {
            int e2 = e - 40960;
            bb = e2 >> 16; int r = e2 & 65535, m = r >> 8; dd = r & 255;
            hp = (m < 128) ? (qry + ((bb * 128 + m) * 2) * 256 + dd)
                           : (neg + ((bb * 128 + (m - 128)) * 2) * 256 + dd);
        }
        float x0 = hp[0], x2 = hp[256];
        float x1 = relb[(bb == rb0) ? 0 : 1][dd];
        stage[wv][lane] = make_uint2(pkrz(x0, x1), pkrz(x2, 1.0f));

        #pragma unroll
        for (int jp = 0; jp < 2; ++jp) {             // 2 chunk-pairs
            // B1 for chunks a=(2jp), b=(2jp+1)
            U8 b1a, b1b;
            #pragma unroll
            for (int q = 0; q < 4; q++) { b1a.w[q] = 0u; b1b.w[q] = 0u; }
            if (g == 0) {
                uint2 sa = stage[wv][(2 * jp) * 16 + col];
                uint2 sb = stage[wv][(2 * jp + 1) * 16 + col];
                b1a.w[0] = sa.x; b1a.w[1] = sa.y;
                b1b.w[0] = sb.x; b1b.w[1] = sb.y;
            }

            // L1: 8 tiles x 2 chunks
            f32x4 c1a[8], c1b[8];
            #pragma unroll
            for (int t = 0; t < 8; t++) {
                c1a[t] = MFMA16(w1f[t], b1a.h, zero4);
                c1b[t] = MFMA16(w1f[t], b1b.h, zero4);
            }

            U8 b2fa[4], b2fb[4];
            #pragma unroll
            for (int kk = 0; kk < 4; kk++) {
                b2fa[kk].w[0] = pkrelu(c1a[2 * kk][0],     c1a[2 * kk][1]);
                b2fa[kk].w[1] = pkrelu(c1a[2 * kk][2],     c1a[2 * kk][3]);
                b2fa[kk].w[2] = pkrelu(c1a[2 * kk + 1][0], c1a[2 * kk + 1][1]);
                b2fa[kk].w[3] = pkrelu(c1a[2 * kk + 1][2], c1a[2 * kk + 1][3]);
                b2fb[kk].w[0] = pkrelu(c1b[2 * kk][0],     c1b[2 * kk][1]);
                b2fb[kk].w[1] = pkrelu(c1b[2 * kk][2],     c1b[2 * kk][3]);
                b2fb[kk].w[2] = pkrelu(c1b[2 * kk + 1][0], c1b[2 * kk + 1][1]);
                b2fb[kk].w[3] = pkrelu(c1b[2 * kk + 1][2], c1b[2 * kk + 1][3]);
            }

            // L2: one LDS weight read feeds both chunks
            f32x4 c2a[4], c2b[4];
            #pragma unroll
            for (int t = 0; t < 4; t++) {
                f32x4 ca = bias2[t], cb = bias2[t];
                #pragma unroll
                for (int kk = 0; kk < 4; kk++) {
                    f16x8 wfr = w2lds[(t * 4 + kk) * 64 + lane];
                    ca = MFMA16(wfr, b2fa[kk].h, ca);
                    cb = MFMA16(wfr, b2fb[kk].h, cb);
                }
                c2a[t] = ca; c2b[t] = cb;
            }

            U8 b3fa[2], b3fb[2];
            #pragma unroll
            for (int kk = 0; kk < 2; kk++) {
                b3fa[kk].w[0] = pkrelu(c2a[2 * kk][0],     c2a[2 * kk][1]);
                b3fa[kk].w[1] = pkrelu(c2a[2 * kk][2],     c2a[2 * kk][3]);
                b3fa[kk].w[2] = pkrelu(c2a[2 * kk + 1][0], c2a[2 * kk + 1][1]);
                b3fa[kk].w[3] = pkrelu(c2a[2 * kk + 1][2], c2a[2 * kk + 1][3]);
                b3fb[kk].w[0] = pkrelu(c2b[2 * kk][0],     c2b[2 * kk][1]);
                b3fb[kk].w[1] = pkrelu(c2b[2 * kk][2],     c2b[2 * kk][3]);
                b3fb[kk].w[2] = pkrelu(c2b[2 * kk + 1][0], c2b[2 * kk + 1][1]);
                b3fb[kk].w[3] = pkrelu(c2b[2 * kk + 1][2], c2b[2 * kk + 1][3]);
            }

            // L3
            f32x4 c3a[2], c3b[2];
            #pragma unroll
            for (int t = 0; t < 2; t++) {
                f32x4 ca = bias3[t], cb = bias3[t];
                #pragma unroll
                for (int kk = 0; kk < 2; kk++) {
                    ca = MFMA16(w3f[t * 2 + kk], b3fa[kk].h, ca);
                    cb = MFMA16(w3f[t * 2 + kk], b3fb[kk].h, cb);
                }
                c3a[t] = ca; c3b[t] = cb;
            }

            U8 b4fa, b4fb;
            b4fa.w[0] = pkrelu(c3a[0][0], c3a[0][1]);
            b4fa.w[1] = pkrelu(c3a[0][2], c3a[0][3]);
            b4fa.w[2] = pkrelu(c3a[1][0], c3a[1][1]);
            b4fa.w[3] = pkrelu(c3a[1][2], c3a[1][3]);
            b4fb.w[0] = pkrelu(c3b[0][0], c3b[0][1]);
            b4fb.w[1] = pkrelu(c3b[0][2], c3b[0][3]);
            b4fb.w[2] = pkrelu(c3b[1][0], c3b[1][1]);
            b4fb.w[3] = pkrelu(c3b[1][2], c3b[1][3]);

            // L4
            f32x4 c4a = MFMA16(w4f, b4fa.h, zero4);
            f32x4 c4b = MFMA16(w4f, b4fb.h, zero4);
            if (lane < 16) {
                wsY[base + it * 64 + (2 * jp) * 16 + lane]     = c4a[0] + b4v;
                wsY[base + it * 64 + (2 * jp + 1) * 16 + lane] = c4b[0] + b4v;
            }
        }
    }
}

// ---------------- scores (+ in-block proto/sneg means): one wave per row ----------------
__global__ __launch_bounds__(256) void k_scores(float* __restrict__ ws, float* __restrict__ out)
{
    __shared__ float proto[16][256];   // 16 KB
    __shared__ float snegs[256];       // 1 KB
    const float* y = ws + OFF_Y;
    int tid = threadIdx.x;
    int row0 = blockIdx.x * 4;
    int b = row0 >> 8;                 // 4 rows per block share b

    // proto[c][d] = mean_n Y[spt_pos: c*1280+n*256+d]
    #pragma unroll
    for (int i = 0; i < 16; i++) {
        int idx = tid + 256 * i;       // 0..4095
        int c = idx >> 8, d = idx & 255;
        float s = 0.f;
        #pragma unroll
        for (int n = 0; n < 5; n++) s += y[c * 1280 + n * 256 + d];
        proto[c][d] = s * 0.2f;
    }
    {
        float s = 0.f;
        #pragma unroll
        for (int n = 0; n < 5; n++) s += y[20480 + b * 1280 + n * 256 + tid];
        snegs[tid] = s * 0.2f;
    }
    __syncthreads();

    int row = row0 + (tid >> 6);
    int lane = tid & 63;
    int m = row & 255;
    const float* q = y + 40960 + row * 256;
    float q0 = q[lane], q1 = q[lane + 64], q2 = q[lane + 128], q3 = q[lane + 192];

    float s[17];
    #pragma unroll
    for (int c = 0; c < 16; c++) {
        float d0 = q0 - proto[c][lane],       d1 = q1 - proto[c][lane + 64];
        float d2 = q2 - proto[c][lane + 128], d3 = q3 - proto[c][lane + 192];
        s[c] = d0 * d0 + d1 * d1 + d2 * d2 + d3 * d3;
    }
    {
        float d0 = q0 - snegs[lane],       d1 = q1 - snegs[lane + 64];
        float d2 = q2 - snegs[lane + 128], d3 = q3 - snegs[lane + 192];
        s[16] = d0 * d0 + d1 * d1 + d2 * d2 + d3 * d3;
    }
    #pragma unroll
    for (int off = 32; off > 0; off >>= 1) {
        #pragma unroll
        for (int c = 0; c < 17; c++) s[c] += __shfl_xor(s[c], off, 64);
    }
    float sumd = 0.f, selfd = 0.f;
    #pragma unroll
    for (int c = 0; c < 16; c++) {
        float dc = sqrtf(s[c]);
        sumd += dc;
        if (c == b) selfd = dc;
    }
    float qpos = -selfd;
    float qneg = -sqrtf(s[16]);
    float relation = -(sumd - selfd) * (1.f / 15.f);
    float delta = qpos - qneg - 0.3f * relation;

    if (lane == 0) {
        out[2 * row] = qpos;
        out[2 * row + 1] = qneg;
        out[8192 + row] = (m < 128) ? 0.f : 1.f;
        if (m < 128) out[12288 + b * 128 + m] = delta;
        else         out[14336 + b * 128 + (m - 128)] = delta;
    }
}

// ---------------- delta_loss finisher: reduce over out[] ----------------
__global__ __launch_bounds__(256) void k_final(float* __restrict__ out)
{
    __shared__ float red[2][256];
    int t = threadIdx.x;
    float sp = 0.f, sn = 0.f;
    #pragma unroll
    for (int i = 0; i < 8; i++) {
        int idx = t + 256 * i;            // 2048 (b, m<128) rows
        int b = idx >> 7, m = idx & 127;
        int row = b * 256 + m;
        sp += out[2 * row];
        sn += out[2 * row + 1];
    }
    red[0][t] = sp; red[1][t] = sn;
    __syncthreads();
    #pragma unroll
    for (int off = 128; off > 0; off >>= 1) {
        if (t < off) { red[0][t] += red[0][t + off]; red[1][t] += red[1][t + off]; }
        __syncthreads();
    }
    if (t == 0) {
        float v = (red[0][0] - red[1][0]) * (1.f / 2048.f) + 1.f;
        out[16384] = fmaxf(v, 0.f);
    }
}

extern "C" void kernel_launch(void* const* d_in, const int* in_sizes, int n_in,
                              void* d_out, int out_size, void* d_ws, size_t ws_size,
                              hipStream_t stream)
{
    const float* sup  = (const float*)d_in[0];
    const float* supn = (const float*)d_in[1];
    const float* qry  = (const float*)d_in[2];
    const float* neg  = (const float*)d_in[3];
    const float* w1   = (const float*)d_in[4];
    const float* b1   = (const float*)d_in[5];
    const float* w2   = (const float*)d_in[6];
    const float* b2   = (const float*)d_in[7];
    const float* w3   = (const float*)d_in[8];
    const float* b3   = (const float*)d_in[9];
    const float* w4   = (const float*)d_in[10];
    const float* b4   = (const float*)d_in[11];
    float* ws  = (float*)d_ws;
    float* out = (float*)d_out;

    k_main  <<<1064, 256, 0, stream>>>(sup, supn, qry, neg, w1, b1, w2, w3, w4, b2, b3, b4, ws);
    k_scores<<<1024, 256, 0, stream>>>(ws, out);
    k_final <<<1,    256, 0, stream>>>(out);
}